// Round 14
// baseline (113.221 us; speedup 1.0000x reference)
//
#include <hip/hip_runtime.h>

// B=8, Cin=64, H=W=128, Cout=64, 9 bilinear taps at (i+0.4, j+0.4).
// v16: FULL separable factorization -> pure 3x3 conv on the doubly-blurred
//      image. All taps share frac offset (0.4,0.4), so bilinear = V o H with
//      H: xh[u] = cx0*x[u] + cx1*x[u+1] (folded into staging, per-lane
//      coefficient trick handles pad edges with ZERO extra masking) and
//      V: the v15 S/T prescale chain. Weights are the RAW w[o,c,k] (no fold).
//   - rs 12 -> 9: MFMA 384->288/block (-25%), wb2 96->72 KB (-25% of the
//     dominant L2 stream, -49 MB chip), A-frag LDS reads -25%.
//   - Cost: +1 clamped scalar load (L1-adjacent) + 2 VALU per staged channel;
//     BLURW loses its gxv cndmasks (edge cols now hold true blurred values).
//   - Structure = v15: barrier-free single-wave 2-slot LDS ring, 2048 x 64,
//     8 LOADT / 6 BLURW / 6 phases, __launch_bounds__(64,2) (~185 regs, fits).

#define CIN   64
#define COUT  64
#define HH    128
#define WW    128

typedef __attribute__((ext_vector_type(8))) short bf16x8;   // 8 bf16 = 4 VGPRs
typedef __attribute__((ext_vector_type(4))) float f32x4;
typedef __attribute__((ext_vector_type(4))) unsigned int u32x4;

__device__ __forceinline__ unsigned short f2bf(float f) {
  unsigned int u = __float_as_uint(f);
  u = (u + 0x7fffu + ((u >> 16) & 1u)) >> 16;   // RNE
  return (unsigned short)u;
}

__device__ __forceinline__ unsigned int cvtpk(float lo, float hi) {
  unsigned int r;                                // D = {bf16(lo), bf16(hi)} RNE
  asm("v_cvt_pk_bf16_f32 %0, %1, %2" : "=v"(r) : "v"(lo), "v"(hi));
  return r;
}

// ---------------------------------------------------------------------------
// Raw-weight reformat: W9[iy*3+ix] = w[o,c,k] for tap k at integer cell
// (iy,ix) = floor(off_k). Both fractional parts live in the image blur.
// Stream layout: wb2[(((p*9+rs)*4 + n)*64 + lane)*8 + j]; consuming lane l
// holds o = n*16+(l&15), ch = p*32+(l>>4)*8+j. (layout lineage v3..v15)
// ---------------------------------------------------------------------------
__global__ void make_wb(const float* __restrict__ wgt,
                        const float* __restrict__ off,
                        unsigned short* __restrict__ wb2)
{
  int id = blockIdx.x * 64 + threadIdx.x;       // 4096 = 64*64
  int o = id >> 6, c = id & 63;
  float W9[9];
  #pragma unroll
  for (int i = 0; i < 9; ++i) W9[i] = 0.f;
  for (int k = 0; k < 9; ++k) {
    int iy = (int)floorf(off[2*k]);             // 0..2
    int ix = (int)floorf(off[2*k+1]);           // 0..2
    W9[iy*3 + ix] += wgt[(o*CIN + c)*9 + k];
  }
  int p = c >> 5, q = (c >> 3) & 3, j = c & 7;
  int n = o >> 4, m15 = o & 15;
  int lanei = q*16 + m15;
  for (int rs = 0; rs < 9; ++rs)
    wb2[(size_t)(((p*9 + rs)*4 + n)*64 + lanei)*8 + j] = f2bf(W9[rs]);
}

// ---------------------------------------------------------------------------
// conv: 1 wave/block, strip = 1 out row x 64 px x 64 Cout, no barriers.
// LDS ring: slot = 68 cols x 4 chunk-slots x 16 B = 4352 B, XOR swizzle.
// Tile col c holds xb_raw col x' = x0-1+c (c = 0..65; 66,67 unused).
// 6 phases: pass p in {0,1} x xb row r in {0,1,2}.
// ---------------------------------------------------------------------------
__global__ __launch_bounds__(64, 2)   // 256-reg cap: ~185 used, 2 waves/SIMD
void conv_mfma(const float* __restrict__ x,
               const float* __restrict__ off,
               const unsigned short* __restrict__ wb2,
               float* __restrict__ out)
{
  __shared__ __align__(16) char lds[17408];     // ring 2x4352 B; epi f32[64][68]

  const int wg  = blockIdx.x;                   // 2048
  const int xcd = wg & 7;
  const int i   = wg >> 3;                      // 0..255
  const int b   = i >> 5;                       // 0..7
  const int r5  = i & 31;
  const int y0  = xcd * 16 + (r5 >> 1);         // XCD-local 16-row band
  const int x0  = (r5 & 1) * 64;                // x half
  const int lane = threadIdx.x;                 // 0..63
  const int m15  = lane & 15;
  const int q    = lane >> 4;

  const float cy1 = off[0] - floorf(off[0]);    // 0.4 (vertical frac)
  const float cy0 = 1.f - cy1;
  const float cx1 = off[1] - floorf(off[1]);    // 0.4 (horizontal frac)
  const float cx0 = 1.f - cx1;

  // ---- horizontal-blur per-lane coefficients (pad folded into coeffs) ----
  // main col c = lane <-> x' = x0-1+lane: xh = ca*x[gxs] + cb*x[gxs+1]
  const int gx  = x0 - 1 + lane;
  const int gxs = gx < 0 ? 0 : gx;              // only lane 0 @ x0=0 clamps
  const float caM = gx < 0 ? cx1 : cx0;         // x'=-1: xh = cx1*x[0]
  const float cbM = gx < 0 ? 0.f : cx1;
  // halo (lanes 0..31): col 64+he <-> x' = x0+63+he; ch pair (2hp, 2hp+1)
  const int he = (lane >> 4) & 1;
  const int hp = lane & 15;
  const int xa = x0 + 63 + he;
  const int xbp = xa + 1;
  const float caH = (xa  <= WW-1) ? cx0 : 0.f;
  const float cbH = (xbp <= WW-1) ? cx1 : 0.f;
  const int xas = (xa  <= WW-1) ? xa  : WW-1;
  const int xbs = (xbp <= WW-1) ? xbp : WW-1;
  const int hoff = (64 + he)*64 + ((hp >> 2) & 3)*16 + (hp & 3)*4;

  int stoff[4];
  #pragma unroll
  for (int c = 0; c < 4; ++c)
    stoff[c] = lane*64 + ((c + (lane >> 2)) & 3)*16;

  int aoff[3];
  #pragma unroll
  for (int s = 0; s < 3; ++s) {
    int c0 = m15 + s;
    aoff[s] = c0*64 + ((q + (c0 >> 2)) & 3)*16;
  }

  f32x4 acc[4][4];
  #pragma unroll
  for (int mi = 0; mi < 4; ++mi)
    #pragma unroll
    for (int nn = 0; nn < 4; ++nn)
      acc[mi][nn] = (f32x4){0.f, 0.f, 0.f, 0.f};

  // staging: T = xh of arrived raw row; S = cy0 * xh(prev row)
  float S[32], T[32];
  float HS0, HS1, HT0, HT1;

// load raw row gy, horizontal-blur into T/HT; zeros if row OOB
#define LOADT(gy_, p_) do {                                                 \
    int gy = (gy_);                                                         \
    if ((unsigned)gy < (unsigned)HH) {                                      \
      const float* ps = x + ((size_t)((b*CIN + (p_)*32)*HH + gy))*WW;       \
      _Pragma("unroll")                                                     \
      for (int cc = 0; cc < 32; ++cc) {                                     \
        float vA = ps[(size_t)cc*HH*WW + gxs];                              \
        float vB = ps[(size_t)cc*HH*WW + gxs + 1];                          \
        T[cc] = caM*vA + cbM*vB;                                            \
      }                                                                     \
      {                                                                     \
        float a0 = ps[(size_t)(2*hp    )*HH*WW + xas];                      \
        float b0 = ps[(size_t)(2*hp    )*HH*WW + xbs];                      \
        float a1 = ps[(size_t)(2*hp + 1)*HH*WW + xas];                      \
        float b1 = ps[(size_t)(2*hp + 1)*HH*WW + xbs];                      \
        HT0 = caH*a0 + cbH*b0;                                              \
        HT1 = caH*a1 + cbH*b1;                                              \
      }                                                                     \
    } else {                                                                \
      _Pragma("unroll")                                                     \
      for (int cc = 0; cc < 32; ++cc) T[cc] = 0.f;                          \
      HT0 = 0.f; HT1 = 0.f;                                                 \
    }                                                                       \
  } while (0)

// S := cy0 * T
#define SETS() do {                                                         \
    _Pragma("unroll")                                                       \
    for (int cc = 0; cc < 32; ++cc) S[cc] = cy0 * T[cc];                    \
    HS0 = cy0 * HT0; HS1 = cy0 * HT1;                                       \
  } while (0)

// write xb row = S + cy1*T to ring slot (no edge masks needed), S := cy0*T
#define BLURW(slot_) do {                                                   \
    char* base = lds + (slot_)*4352;                                        \
    _Pragma("unroll")                                                       \
    for (int c = 0; c < 4; ++c) {                                           \
      unsigned int pk[4];                                                   \
      _Pragma("unroll")                                                     \
      for (int w = 0; w < 4; ++w)                                           \
        pk[w] = cvtpk(S[c*8 + 2*w    ] + cy1 * T[c*8 + 2*w    ],            \
                      S[c*8 + 2*w + 1] + cy1 * T[c*8 + 2*w + 1]);           \
      *(u32x4*)(base + stoff[c]) = *(u32x4*)pk;                             \
    }                                                                       \
    {                                                                       \
      unsigned int hw = cvtpk(HS0 + cy1*HT0, HS1 + cy1*HT1);                \
      if (lane < 32) *(unsigned int*)(base + hoff) = hw;                    \
    }                                                                       \
    SETS();                                                                 \
  } while (0)

  // COMPUTE(k): pass = k/3, xb row r = k%3, ring slot k&1; 9 rs total.
  auto COMPUTE = [&](int k) {
    const int r = k % 3;
    const char* ab = lds + (k & 1)*4352;
    const char* wb = (const char*)wb2 + (size_t)(k / 3)*36864 + (size_t)lane*16;
    #pragma unroll
    for (int s = 0; s < 3; ++s) {
      bf16x8 afr[4];
      #pragma unroll
      for (int mi = 0; mi < 4; ++mi)
        afr[mi] = *(const bf16x8*)(ab + aoff[s] + mi*1024);
      const char* w0 = wb + (size_t)(r*3 + s)*4096;
      bf16x8 bfr[4];
      #pragma unroll
      for (int n = 0; n < 4; ++n)
        bfr[n] = *(const bf16x8*)(w0 + n*1024);
      #pragma unroll
      for (int mi = 0; mi < 4; ++mi)
        #pragma unroll
        for (int nn = 0; nn < 4; ++nn)
          acc[mi][nn] = __builtin_amdgcn_mfma_f32_16x16x32_bf16(afr[mi], bfr[nn], acc[mi][nn], 0, 0, 0);
    }
  };

  // ---- 6-phase barrier-free pipeline (v15 schedule) ----
  LOADT(y0 - 1, 0); SETS();                     // S = cy0 * xh(-1)
  LOADT(y0,     0);
  BLURW(0);                                     // xb0; S = cy0*xh0
  LOADT(y0 + 1, 0);
  COMPUTE(0);
  BLURW(1);                                     // xb1; S = cy0*xh1
  LOADT(y0 + 2, 0);
  COMPUTE(1);
  BLURW(0);                                     // xb2
  LOADT(y0 - 1, 1);                             // pass-1 row -1 (in flight)
  COMPUTE(2);
  SETS();                                       // S = cy0 * xh(-1) pass 1
  LOADT(y0,     1);
  BLURW(1);                                     // xb0'
  LOADT(y0 + 1, 1);
  COMPUTE(3);
  BLURW(0);                                     // xb1'
  LOADT(y0 + 2, 1);
  COMPUTE(4);
  BLURW(1);                                     // xb2'
  COMPUTE(5);

#undef LOADT
#undef SETS
#undef BLURW

  // ---- epilogue: transpose through LDS (single wave), coalesced stores ----
  float* epi = (float*)lds;
  #pragma unroll
  for (int mi = 0; mi < 4; ++mi)
    #pragma unroll
    for (int nn = 0; nn < 4; ++nn) {
      int o  = nn*16 + m15;
      int px = mi*16 + q*4;                     // D row = q*4 + reg
      *(f32x4*)&epi[o*68 + px] = acc[mi][nn];
    }
  #pragma unroll
  for (int i2 = 0; i2 < 16; ++i2) {
    int o  = i2*4 + q;
    int px = m15*4;
    f32x4 v = *(const f32x4*)&epi[o*68 + px];
    *(f32x4*)&out[(((size_t)(b*COUT + o))*HH + y0)*WW + x0 + px] = v;
  }
}

// ---------------------------------------------------------------------------
extern "C" void kernel_launch(void* const* d_in, const int* in_sizes, int n_in,
                              void* d_out, int out_size, void* d_ws, size_t ws_size,
                              hipStream_t stream)
{
  const float* x   = (const float*)d_in[0];   // [8,64,128,128] fp32
  const float* wgt = (const float*)d_in[1];   // [64,64,9] fp32
  const float* off = (const float*)d_in[2];   // [9,2] fp32
  float* out = (float*)d_out;                 // [8,64,128,128] fp32
  unsigned short* wb2 = (unsigned short*)d_ws;// 72 KB stream-layout weights

  make_wb<<<64, 64, 0, stream>>>(wgt, off, wb2);
  conv_mfma<<<2048, 64, 0, stream>>>(x, off, wb2, out);
}

// Round 15
// 110.445 us; speedup vs baseline: 1.0251x; 1.0251x over previous
//
#include <hip/hip_runtime.h>

// B=8, Cin=64, H=W=128, Cout=64, 9 bilinear taps at (i+0.4, j+0.4).
// v17: 3x3 separable conv with SHUFFLE-based horizontal blur.
//   - v16 post-mortem: 3x3 math verified but doubling the main staging loads
//     (2 per channel) cost more than -25% MFMA/wb2 saved (113.2 vs 101.6).
//   - v17: lane l already holds raw x[x0-1+l]; neighbor x[x0+l] comes from
//     lane l+1 via __shfl_down(.,1) (1 ds_bpermute/channel, no 2nd load).
//     Main load count = v15's 32/LOADT. Halo extends to cols 63..66
//     (he = lane>>4, all 64 lanes, no divergence; col 63's garbage main write
//     is overwritten in-order by the halo write; col 66 is scratch).
//     Pad edges via per-lane coefficients only - no masks in BLURW.
//   - Keeps: 9 rs (-25% MFMA vs v15), wb2 72 KB (-25% L2 stream), raw
//     weights, barrier-free single-wave 2-slot LDS ring, 2048 x 64,
//     8 LOADT / 6 BLURW / 6 phases, __launch_bounds__(64,2).

#define CIN   64
#define COUT  64
#define HH    128
#define WW    128

typedef __attribute__((ext_vector_type(8))) short bf16x8;   // 8 bf16 = 4 VGPRs
typedef __attribute__((ext_vector_type(4))) float f32x4;
typedef __attribute__((ext_vector_type(4))) unsigned int u32x4;

__device__ __forceinline__ unsigned short f2bf(float f) {
  unsigned int u = __float_as_uint(f);
  u = (u + 0x7fffu + ((u >> 16) & 1u)) >> 16;   // RNE
  return (unsigned short)u;
}

__device__ __forceinline__ unsigned int cvtpk(float lo, float hi) {
  unsigned int r;                                // D = {bf16(lo), bf16(hi)} RNE
  asm("v_cvt_pk_bf16_f32 %0, %1, %2" : "=v"(r) : "v"(lo), "v"(hi));
  return r;
}

// ---------------------------------------------------------------------------
// Raw-weight reformat (v16-verified): W9[iy*3+ix] = sum of w[o,c,k] whose tap
// floor is (iy,ix). Both fractional parts live in the image blur.
// Stream layout: wb2[(((p*9+rs)*4 + n)*64 + lane)*8 + j].
// ---------------------------------------------------------------------------
__global__ void make_wb(const float* __restrict__ wgt,
                        const float* __restrict__ off,
                        unsigned short* __restrict__ wb2)
{
  int id = blockIdx.x * 64 + threadIdx.x;       // 4096 = 64*64
  int o = id >> 6, c = id & 63;
  float W9[9];
  #pragma unroll
  for (int i = 0; i < 9; ++i) W9[i] = 0.f;
  for (int k = 0; k < 9; ++k) {
    int iy = (int)floorf(off[2*k]);             // 0..2
    int ix = (int)floorf(off[2*k+1]);           // 0..2
    W9[iy*3 + ix] += wgt[(o*CIN + c)*9 + k];
  }
  int p = c >> 5, q = (c >> 3) & 3, j = c & 7;
  int n = o >> 4, m15 = o & 15;
  int lanei = q*16 + m15;
  for (int rs = 0; rs < 9; ++rs)
    wb2[(size_t)(((p*9 + rs)*4 + n)*64 + lanei)*8 + j] = f2bf(W9[rs]);
}

// ---------------------------------------------------------------------------
// conv: 1 wave/block, strip = 1 out row x 64 px x 64 Cout, no barriers.
// LDS ring: slot = 68 cols x 4 chunk-slots x 16 B = 4352 B, XOR swizzle.
// Tile col c holds xb col x' = x0-1+c (cols 0..65 used; 66 scratch).
// 6 phases: pass p in {0,1} x xb row r in {0,1,2}.
// ---------------------------------------------------------------------------
__global__ __launch_bounds__(64, 2)   // 256-reg cap: ~200 peak, 2 waves/SIMD
void conv_mfma(const float* __restrict__ x,
               const float* __restrict__ off,
               const unsigned short* __restrict__ wb2,
               float* __restrict__ out)
{
  __shared__ __align__(16) char lds[17408];     // ring 2x4352 B; epi f32[64][68]

  const int wg  = blockIdx.x;                   // 2048
  const int xcd = wg & 7;
  const int i   = wg >> 3;                      // 0..255
  const int b   = i >> 5;                       // 0..7
  const int r5  = i & 31;
  const int y0  = xcd * 16 + (r5 >> 1);         // XCD-local 16-row band
  const int x0  = (r5 & 1) * 64;                // x half
  const int lane = threadIdx.x;                 // 0..63
  const int m15  = lane & 15;
  const int q    = lane >> 4;

  const float cy1 = off[0] - floorf(off[0]);    // 0.4 (vertical frac)
  const float cy0 = 1.f - cy1;
  const float cx1 = off[1] - floorf(off[1]);    // 0.4 (horizontal frac)
  const float cx0 = 1.f - cx1;

  // ---- main cols: raw load index + blur coefficients (pad in coeffs) ----
  // lane l <-> col l <-> x' = x0-1+l: xh = caM*R[l] + cbM*R[l+1(shfl)]
  const int gx  = x0 - 1 + lane;
  const int gxc = gx < 0 ? 0 : gx;              // only lane 0 @ x0=0 clamps
  const float caM = gx < 0 ? cx1 : cx0;         // x'=-1: xh = cx1*x[0]
  const float cbM = gx < 0 ? 0.f : cx1;
  // ---- halo cols 63..66 (col 66 = scratch): he = lane>>4, ch pair hp ----
  const int he = lane >> 4;                     // 0..3
  const int hp = lane & 15;
  const int xa  = x0 + 62 + he;                 // x' = x0+62+he
  const int xbp = xa + 1;
  const float caH = (xa  <= WW-1) ? cx0 : 0.f;
  const float cbH = (xbp <= WW-1) ? cx1 : 0.f;
  const int xas = (xa  <= WW-1) ? xa  : WW-1;
  const int xbs = (xbp <= WW-1) ? xbp : WW-1;
  const int hcol = 63 + he;
  const int hoff = hcol*64 + (((hp >> 2) + (hcol >> 2)) & 3)*16 + (hp & 3)*4;

  int stoff[4];
  #pragma unroll
  for (int c = 0; c < 4; ++c)
    stoff[c] = lane*64 + ((c + (lane >> 2)) & 3)*16;

  int aoff[3];
  #pragma unroll
  for (int s = 0; s < 3; ++s) {
    int c0 = m15 + s;
    aoff[s] = c0*64 + ((q + (c0 >> 2)) & 3)*16;
  }

  f32x4 acc[4][4];
  #pragma unroll
  for (int mi = 0; mi < 4; ++mi)
    #pragma unroll
    for (int nn = 0; nn < 4; ++nn)
      acc[mi][nn] = (f32x4){0.f, 0.f, 0.f, 0.f};

  // staging: T = xh (horizontally blurred arrived row); S = cy0 * xh(prev)
  float S[32], T[32];
  float HS0, HS1, HT0, HT1;

// load raw row gy, horizontal-blur via shfl_down into T/HT; zeros if OOB
#define LOADT(gy_, p_) do {                                                 \
    int gy = (gy_);                                                         \
    if ((unsigned)gy < (unsigned)HH) {                                      \
      const float* ps = x + ((size_t)((b*CIN + (p_)*32)*HH + gy))*WW;       \
      _Pragma("unroll")                                                     \
      for (int cc = 0; cc < 32; ++cc) {                                     \
        float rv = ps[(size_t)cc*HH*WW + gxc];                              \
        float nb = __shfl_down(rv, 1);                                      \
        T[cc] = caM*rv + cbM*nb;                                            \
      }                                                                     \
      {                                                                     \
        float a0 = ps[(size_t)(2*hp    )*HH*WW + xas];                      \
        float b0 = ps[(size_t)(2*hp    )*HH*WW + xbs];                      \
        float a1 = ps[(size_t)(2*hp + 1)*HH*WW + xas];                      \
        float b1 = ps[(size_t)(2*hp + 1)*HH*WW + xbs];                      \
        HT0 = caH*a0 + cbH*b0;                                              \
        HT1 = caH*a1 + cbH*b1;                                              \
      }                                                                     \
    } else {                                                                \
      _Pragma("unroll")                                                     \
      for (int cc = 0; cc < 32; ++cc) T[cc] = 0.f;                          \
      HT0 = 0.f; HT1 = 0.f;                                                 \
    }                                                                       \
  } while (0)

// S := cy0 * T
#define SETS() do {                                                         \
    _Pragma("unroll")                                                       \
    for (int cc = 0; cc < 32; ++cc) S[cc] = cy0 * T[cc];                    \
    HS0 = cy0 * HT0; HS1 = cy0 * HT1;                                       \
  } while (0)

// write xb row = S + cy1*T to ring slot; main cols first, halo (63..66)
// overwrites col 63's garbage in program order. Then S := cy0*T.
#define BLURW(slot_) do {                                                   \
    char* base = lds + (slot_)*4352;                                        \
    _Pragma("unroll")                                                       \
    for (int c = 0; c < 4; ++c) {                                           \
      unsigned int pk[4];                                                   \
      _Pragma("unroll")                                                     \
      for (int w = 0; w < 4; ++w)                                           \
        pk[w] = cvtpk(S[c*8 + 2*w    ] + cy1 * T[c*8 + 2*w    ],            \
                      S[c*8 + 2*w + 1] + cy1 * T[c*8 + 2*w + 1]);           \
      *(u32x4*)(base + stoff[c]) = *(u32x4*)pk;                             \
    }                                                                       \
    {                                                                       \
      unsigned int hw = cvtpk(HS0 + cy1*HT0, HS1 + cy1*HT1);                \
      *(unsigned int*)(base + hoff) = hw;                                   \
    }                                                                       \
    SETS();                                                                 \
  } while (0)

  // COMPUTE(k): pass = k/3, xb row r = k%3, ring slot k&1; 9 rs total.
  auto COMPUTE = [&](int k) {
    const int r = k % 3;
    const char* ab = lds + (k & 1)*4352;
    const char* wb = (const char*)wb2 + (size_t)(k / 3)*36864 + (size_t)lane*16;
    #pragma unroll
    for (int s = 0; s < 3; ++s) {
      bf16x8 afr[4];
      #pragma unroll
      for (int mi = 0; mi < 4; ++mi)
        afr[mi] = *(const bf16x8*)(ab + aoff[s] + mi*1024);
      const char* w0 = wb + (size_t)(r*3 + s)*4096;
      bf16x8 bfr[4];
      #pragma unroll
      for (int n = 0; n < 4; ++n)
        bfr[n] = *(const bf16x8*)(w0 + n*1024);
      #pragma unroll
      for (int mi = 0; mi < 4; ++mi)
        #pragma unroll
        for (int nn = 0; nn < 4; ++nn)
          acc[mi][nn] = __builtin_amdgcn_mfma_f32_16x16x32_bf16(afr[mi], bfr[nn], acc[mi][nn], 0, 0, 0);
    }
  };

  // ---- 6-phase barrier-free pipeline (v15 schedule) ----
  LOADT(y0 - 1, 0); SETS();                     // S = cy0 * xh(-1)
  LOADT(y0,     0);
  BLURW(0);                                     // xb0; S = cy0*xh0
  LOADT(y0 + 1, 0);
  COMPUTE(0);
  BLURW(1);                                     // xb1; S = cy0*xh1
  LOADT(y0 + 2, 0);
  COMPUTE(1);
  BLURW(0);                                     // xb2
  LOADT(y0 - 1, 1);                             // pass-1 row -1 (in flight)
  COMPUTE(2);
  SETS();                                       // S = cy0 * xh(-1) pass 1
  LOADT(y0,     1);
  BLURW(1);                                     // xb0'
  LOADT(y0 + 1, 1);
  COMPUTE(3);
  BLURW(0);                                     // xb1'
  LOADT(y0 + 2, 1);
  COMPUTE(4);
  BLURW(1);                                     // xb2'
  COMPUTE(5);

#undef LOADT
#undef SETS
#undef BLURW

  // ---- epilogue: transpose through LDS (single wave), coalesced stores ----
  float* epi = (float*)lds;
  #pragma unroll
  for (int mi = 0; mi < 4; ++mi)
    #pragma unroll
    for (int nn = 0; nn < 4; ++nn) {
      int o  = nn*16 + m15;
      int px = mi*16 + q*4;                     // D row = q*4 + reg
      *(f32x4*)&epi[o*68 + px] = acc[mi][nn];
    }
  #pragma unroll
  for (int i2 = 0; i2 < 16; ++i2) {
    int o  = i2*4 + q;
    int px = m15*4;
    f32x4 v = *(const f32x4*)&epi[o*68 + px];
    *(f32x4*)&out[(((size_t)(b*COUT + o))*HH + y0)*WW + x0 + px] = v;
  }
}

// ---------------------------------------------------------------------------
extern "C" void kernel_launch(void* const* d_in, const int* in_sizes, int n_in,
                              void* d_out, int out_size, void* d_ws, size_t ws_size,
                              hipStream_t stream)
{
  const float* x   = (const float*)d_in[0];   // [8,64,128,128] fp32
  const float* wgt = (const float*)d_in[1];   // [64,64,9] fp32
  const float* off = (const float*)d_in[2];   // [9,2] fp32
  float* out = (float*)d_out;                 // [8,64,128,128] fp32
  unsigned short* wb2 = (unsigned short*)d_ws;// 72 KB stream-layout weights

  make_wb<<<64, 64, 0, stream>>>(wgt, off, wb2);
  conv_mfma<<<2048, 64, 0, stream>>>(x, off, wb2, out);
}